// Round 5
// baseline (132.533 us; speedup 1.0000x reference)
//
#include <hip/hip_runtime.h>
#include <math.h>

// Problem constants
static constexpr int PB = 32;      // batch
static constexpr int PL = 4096;    // seq len
static constexpr int PC = 64;      // in channels
static constexpr int PD = 128;     // out channels
static constexpr int PK = 2048;    // TOPK = L/2

typedef __attribute__((ext_vector_type(8))) short bf16x8;
typedef __attribute__((ext_vector_type(4))) float f32x4;

#define MFMA_BF16(A, B, C) __builtin_amdgcn_mfma_f32_16x16x32_bf16(A, B, C, 0, 0, 0)

__device__ inline short f2bf(float f) {
  unsigned u = __float_as_uint(f);
  u += 0x7FFFu + ((u >> 16) & 1u);   // RNE
  return (short)(u >> 16);
}

__device__ inline unsigned f2key(float f) {
  unsigned u = __float_as_uint(f);
  return (u & 0x80000000u) ? ~u : (u | 0x80000000u);   // sortable uint
}

// ---------------- kernel 1: scores (B,L) + x->bf16 copy + W panel transforms --
// Grid = 1024 blocks x 256 threads; 128 rows/block (8 iters of 16 rows) for
// deep independent-load pipelining. Blocks 0/1 additionally transform
// sparse_w/full_w (f32 CxD) into fragment-ordered bf16 panels in workspace;
// first block of each batch zeroes agg (consumed after kernel boundary).
__global__ __launch_bounds__(256) void scores_kernel(
    const float* __restrict__ x, const float* __restrict__ score_w,
    const float* __restrict__ score_b, const float* __restrict__ sparse_w,
    const float* __restrict__ full_w, float* __restrict__ scores,
    short* __restrict__ xbf, unsigned* __restrict__ wtfg,
    float* __restrict__ agg) {
  int tid = threadIdx.x;
  int blk = blockIdx.x;

  if (blk < 2) {
    const float* w = (blk == 0) ? sparse_w : full_w;
    unsigned* dst = wtfg + blk * 4096;
    for (int i = tid; i < 4096; i += 256) {
      int d = i & 127, cp = i >> 7, c = cp * 2;
      float va = w[(size_t)c * PD + d];
      float vb = w[(size_t)(c + 1) * PD + d];
      unsigned lo = (unsigned short)f2bf(va);
      unsigned hi = (unsigned short)f2bf(vb);
      int t = d >> 4, dl = d & 15, h = c >> 5, cq = (c >> 3) & 3, jp = (c & 7) >> 1;
      dst[(((t * 2 + h) * 4 + cq) * 16 + dl) * 4 + jp] = lo | (hi << 16);
    }
  }
  // zero agg for batch b = blk>>5 (32 blocks per batch; first block does it)
  if ((blk & 31) == 0 && tid < PD)
    agg[(size_t)(blk >> 5) * PD + tid] = 0.f;

  int r  = tid >> 4;
  int c4 = tid & 15;
  float4 wv = *(const float4*)(score_w + c4 * 4);
  float sb0 = score_b[0];

  #pragma unroll
  for (int it = 0; it < 8; ++it) {
    int row = blk * 128 + it * 16 + r;
    float4 xv = *(const float4*)(x + (size_t)row * PC + c4 * 4);
    short4 xbv;
    xbv.x = f2bf(xv.x); xbv.y = f2bf(xv.y); xbv.z = f2bf(xv.z); xbv.w = f2bf(xv.w);
    *(short4*)(xbf + (size_t)row * PC + c4 * 4) = xbv;
    float v = xv.x * wv.x + xv.y * wv.y + xv.z * wv.z + xv.w * wv.w;
    #pragma unroll
    for (int off = 1; off < 16; off <<= 1) v += __shfl_xor(v, off);
    if (c4 == 0) scores[row] = v + sb0;
  }
}

// ---------------- shared staging: 16 KB fragment-ordered W panel -> LDS ------
__device__ inline void stage_wtf(const unsigned* __restrict__ g, unsigned* lds, int tid) {
  #pragma unroll
  for (int q = 0; q < 4; ++q) {
    uint4 v = *(const uint4*)(g + q * 1024 + tid * 4);
    *(uint4*)(lds + q * 1024 + tid * 4) = v;
  }
}

// ---------------- suffix-scan helper for select (N buckets per thread) ------
// hbuf[k] := #keys in buckets >= k, for k in [0, 256*N); hbuf[256*N] = 0.
// cnt must already be in registers; caller synced after reading cnt from hbuf.
template <int N>
__device__ inline void suffix_scan(const unsigned* cnt, int tid, int lane, int wid,
                                   unsigned* hbuf, unsigned* wsum) {
  unsigned tsum = 0;
  #pragma unroll
  for (int i = 0; i < N; ++i) tsum += cnt[i];
  unsigned v = tsum;
  #pragma unroll
  for (int off = 1; off < 64; off <<= 1) {
    unsigned t = __shfl_down(v, off);
    if (lane + off < 64) v += t;
  }
  if (lane == 0) wsum[wid] = v;      // sum over this wave's threads >= own
  __syncthreads();
  unsigned add = 0;
  #pragma unroll
  for (int w = 0; w < 4; ++w) if (w > wid) add += wsum[w];
  unsigned run = v + add - tsum;     // suffix count starting at thread tid+1
  #pragma unroll
  for (int i = N - 1; i >= 0; --i) { run += cnt[i]; hbuf[tid * N + i] = run; }
  if (tid == 0) hbuf[256 * N] = 0;
  __syncthreads();
}

// ---------------- kernel 2: fused top-K select + sparse GEMM + gelu + agg ---
// 512 blocks = 16 per batch. EACH block redundantly runs the exact radix
// select for its batch (keys: 16 VGPRs/thread; deterministic -> identical
// threshold in all 16 blocks), keeps only its own 128 selected slots, then
// MFMA-GEMMs those rows. Select uses 3 rounds (11/11/10 bits) over a single
// 2048-bucket LDS histogram -- one less serial round than 8-bit radix.
// Ties at threshold by lowest index (matches lax.top_k). Exact.
__global__ __launch_bounds__(256, 3) void sparse_kernel(
    const short* __restrict__ xbf, const unsigned* __restrict__ wtfg,
    const float* __restrict__ sparse_b, const float* __restrict__ scores,
    float* __restrict__ agg) {
  __shared__ unsigned WTf[4096];      // 16 KB
  __shared__ float red[PD];
  __shared__ unsigned hbuf[2049];     // 8.2 KB histogram/scan buffer
  __shared__ unsigned wsum[4];
  __shared__ unsigned sh_pfx, sh_need;
  __shared__ int sel_l[128];          // this block's 128 selected rows

  int tid = threadIdx.x;
  stage_wtf(wtfg, WTf, tid);          // loads in flight during select phase
  if (tid < PD) red[tid] = 0.f;

  int lane = tid & 63, wid = tid >> 6;
  int b  = blockIdx.x >> 4;           // 16 row-blocks of 128 per batch
  int rb = blockIdx.x & 15;
  const float* sc = scores + (size_t)b * PL;

  // ---- select phase (identical in all 16 blocks of this batch) ----
  unsigned k[16];
  #pragma unroll
  for (int q = 0; q < 4; ++q) {
    float4 f = *(const float4*)(sc + tid * 16 + q * 4);
    k[q * 4 + 0] = f2key(f.x);
    k[q * 4 + 1] = f2key(f.y);
    k[q * 4 + 2] = f2key(f.z);
    k[q * 4 + 3] = f2key(f.w);
  }
  if (tid == 0) sh_need = (unsigned)PK;

  // ---- round 1: bits [31:21], 2048 buckets ----
  {
    #pragma unroll
    for (int i = 0; i < 8; ++i) hbuf[tid * 8 + i] = 0u;
    __syncthreads();                         // publishes sh_need too
    unsigned need = sh_need;
    #pragma unroll
    for (int j = 0; j < 16; ++j) atomicAdd(&hbuf[k[j] >> 21], 1u);
    __syncthreads();
    unsigned cnt[8];
    #pragma unroll
    for (int i = 0; i < 8; ++i) cnt[i] = hbuf[tid * 8 + i];
    __syncthreads();
    suffix_scan<8>(cnt, tid, lane, wid, hbuf, wsum);
    #pragma unroll
    for (int i = 0; i < 8; ++i) {
      int kk = tid * 8 + i;
      if (hbuf[kk] >= need && hbuf[kk + 1] < need) {
        sh_pfx  = (unsigned)kk << 21;
        sh_need = need - hbuf[kk + 1];
      }
    }
  }

  // ---- round 2: bits [20:10], 2048 buckets over surviving keys ----
  {
    #pragma unroll
    for (int i = 0; i < 8; ++i) hbuf[tid * 8 + i] = 0u;
    __syncthreads();                         // publishes sh_pfx/sh_need
    unsigned pfx = sh_pfx, need = sh_need;
    #pragma unroll
    for (int j = 0; j < 16; ++j) {
      if ((k[j] & 0xFFE00000u) == pfx)
        atomicAdd(&hbuf[(k[j] >> 10) & 2047u], 1u);
    }
    __syncthreads();
    unsigned cnt[8];
    #pragma unroll
    for (int i = 0; i < 8; ++i) cnt[i] = hbuf[tid * 8 + i];
    __syncthreads();
    suffix_scan<8>(cnt, tid, lane, wid, hbuf, wsum);
    #pragma unroll
    for (int i = 0; i < 8; ++i) {
      int kk = tid * 8 + i;
      if (hbuf[kk] >= need && hbuf[kk + 1] < need) {
        sh_pfx  = pfx | ((unsigned)kk << 10);
        sh_need = need - hbuf[kk + 1];
      }
    }
  }

  // ---- round 3: bits [9:0], 1024 buckets ----
  {
    #pragma unroll
    for (int i = 0; i < 4; ++i) hbuf[tid * 4 + i] = 0u;
    __syncthreads();
    unsigned pfx = sh_pfx, need = sh_need;
    #pragma unroll
    for (int j = 0; j < 16; ++j) {
      if ((k[j] & 0xFFFFFC00u) == pfx)
        atomicAdd(&hbuf[k[j] & 1023u], 1u);
    }
    __syncthreads();
    unsigned cnt[4];
    #pragma unroll
    for (int i = 0; i < 4; ++i) cnt[i] = hbuf[tid * 4 + i];
    __syncthreads();
    suffix_scan<4>(cnt, tid, lane, wid, hbuf, wsum);
    #pragma unroll
    for (int i = 0; i < 4; ++i) {
      int kk = tid * 4 + i;
      if (hbuf[kk] >= need && hbuf[kk + 1] < need) {
        sh_pfx  = pfx | (unsigned)kk;
        sh_need = need - hbuf[kk + 1];
      }
    }
  }
  __syncthreads();
  unsigned T = sh_pfx;          // K-th largest key
  unsigned needEq = sh_need;    // how many ==T to take (lowest indices)

  // each thread owns 16 contiguous indices (base = tid*16), keys in regs
  int base = tid * 16;
  unsigned ceq = 0;
  #pragma unroll
  for (int j = 0; j < 16; ++j) ceq += (k[j] == T);

  // exclusive prefix scan of eq counts (wave shfl + cross-wave)
  unsigned v1 = ceq;
  #pragma unroll
  for (int off = 1; off < 64; off <<= 1) {
    unsigned t = __shfl_up(v1, off);
    if (lane >= off) v1 += t;
  }
  if (lane == 63) wsum[wid] = v1;
  __syncthreads();
  unsigned add1 = 0;
  #pragma unroll
  for (int w = 0; w < 4; ++w) if (w < wid) add1 += wsum[w];
  unsigned eqbase = v1 + add1 - ceq;
  __syncthreads();                        // protect wsum before reuse

  // count selected in my chunk
  unsigned csel = 0, eqr = eqbase;
  #pragma unroll
  for (int j = 0; j < 16; ++j) {
    if (k[j] > T) csel++;
    else if (k[j] == T) { if (eqr < needEq) csel++; eqr++; }
  }
  unsigned v2 = csel;
  #pragma unroll
  for (int off = 1; off < 64; off <<= 1) {
    unsigned t = __shfl_up(v2, off);
    if (lane >= off) v2 += t;
  }
  if (lane == 63) wsum[wid] = v2;
  __syncthreads();
  unsigned add2 = 0;
  #pragma unroll
  for (int w = 0; w < 4; ++w) if (w < wid) add2 += wsum[w];
  unsigned pos = v2 + add2 - csel;

  // keep only this block's slot window [rb*128, rb*128+128)
  int lo = rb * 128;
  eqr = eqbase;
  #pragma unroll
  for (int j = 0; j < 16; ++j) {
    bool sel;
    if (k[j] > T) sel = true;
    else if (k[j] == T) { sel = (eqr < needEq); eqr++; }
    else sel = false;
    if (sel) {
      int p = (int)pos++;
      if (p >= lo && p < lo + 128) sel_l[p - lo] = base + j;
    }
  }
  __syncthreads();                       // sel_l + WTf + red all ready

  // ---- GEMM phase: wave computes 32 selected rows x 128 cols ----
  int ln = lane & 15, quad = lane >> 4;
  int jl = wid * 32 + ln;
  int r0 = sel_l[jl], r1 = sel_l[jl + 16];

  const short* xb = xbf + (size_t)b * PL * PC;
  const short* p0 = xb + (size_t)r0 * PC + quad * 8;
  const short* p1 = xb + (size_t)r1 * PC + quad * 8;
  bf16x8 a00 = *(const bf16x8*)p0, a01 = *(const bf16x8*)(p0 + 32);
  bf16x8 a10 = *(const bf16x8*)p1, a11 = *(const bf16x8*)(p1 + 32);

  f32x4 acc0[8], acc1[8];
  #pragma unroll
  for (int t = 0; t < 8; ++t) { acc0[t] = (f32x4){0.f,0.f,0.f,0.f}; acc1[t] = (f32x4){0.f,0.f,0.f,0.f}; }

  const short* wb = (const short*)WTf + lane * 8;   // contiguous per-wave reads
  #pragma unroll
  for (int t = 0; t < 8; ++t) {
    bf16x8 b0 = *(const bf16x8*)(wb + (2 * t) * 512);
    bf16x8 b1 = *(const bf16x8*)(wb + (2 * t + 1) * 512);
    acc0[t] = MFMA_BF16(a00, b0, acc0[t]);
    acc0[t] = MFMA_BF16(a01, b1, acc0[t]);
    acc1[t] = MFMA_BF16(a10, b0, acc1[t]);
    acc1[t] = MFMA_BF16(a11, b1, acc1[t]);
  }

  // gelu(feat + bias), sum over this wave's 32 rows per column
  #pragma unroll
  for (int t = 0; t < 8; ++t) {
    float bias = sparse_b[t * 16 + ln];
    float s = 0.f;
    #pragma unroll
    for (int i = 0; i < 4; ++i) {
      float v0 = acc0[t][i] + bias;
      s += 0.5f * v0 * (1.0f + erff(v0 * 0.70710678118654752f));
      float v1 = acc1[t][i] + bias;
      s += 0.5f * v1 * (1.0f + erff(v1 * 0.70710678118654752f));
    }
    s += __shfl_xor(s, 16);
    s += __shfl_xor(s, 32);     // sum over all 32 rows of the wave
    if (quad == 0) atomicAdd(&red[t * 16 + ln], s);
  }
  __syncthreads();
  if (tid < PD) atomicAdd(&agg[(size_t)b * PD + tid], red[tid]);
}

// ---------------- kernel 3: full GEMM + agg + LayerNorm + store -------------
// block = 256 = 4 waves; each wave: 32 rows (2 groups of 16) x 128 cols.
__global__ __launch_bounds__(256, 3) void full_ln_kernel(
    const short* __restrict__ xbf, const unsigned* __restrict__ wtfg,
    const float* __restrict__ full_b, const float* __restrict__ ln_g,
    const float* __restrict__ ln_b, const float* __restrict__ agg,
    float* __restrict__ out) {
  __shared__ unsigned WTf[4096];   // 16 KB
  int tid = threadIdx.x;
  stage_wtf(wtfg, WTf, tid);
  __syncthreads();

  int lane = tid & 63, wid = tid >> 6;
  int ln = lane & 15, quad = lane >> 4;
  int rowbase = blockIdx.x * 128 + wid * 32;   // 32 rows per wave
  int b = rowbase >> 12;                       // L = 4096

  const float invK = 1.0f / (float)PK;
  float bias[8], gg[8], bb[8];
  #pragma unroll
  for (int t = 0; t < 8; ++t) {
    int d = t * 16 + ln;
    bias[t] = full_b[d] + agg[(size_t)b * PD + d] * invK;
    gg[t] = ln_g[d];
    bb[t] = ln_b[d];
  }

  const short* p0 = xbf + (size_t)(rowbase + ln) * PC + quad * 8;
  const short* p1 = xbf + (size_t)(rowbase + 16 + ln) * PC + quad * 8;
  bf16x8 a00 = *(const bf16x8*)p0, a01 = *(const bf16x8*)(p0 + 32);
  bf16x8 a10 = *(const bf16x8*)p1, a11 = *(const bf16x8*)(p1 + 32);

  f32x4 acc0[8], acc1[8];
  #pragma unroll
  for (int t = 0; t < 8; ++t) { acc0[t] = (f32x4){0.f,0.f,0.f,0.f}; acc1[t] = (f32x4){0.f,0.f,0.f,0.f}; }

  const short* wb = (const short*)WTf + lane * 8;
  #pragma unroll
  for (int t = 0; t < 8; ++t) {
    bf16x8 b0 = *(const bf16x8*)(wb + (2 * t) * 512);
    bf16x8 b1 = *(const bf16x8*)(wb + (2 * t + 1) * 512);
    acc0[t] = MFMA_BF16(a00, b0, acc0[t]);
    acc0[t] = MFMA_BF16(a01, b1, acc0[t]);
    acc1[t] = MFMA_BF16(a10, b0, acc1[t]);
    acc1[t] = MFMA_BF16(a11, b1, acc1[t]);
  }

  // h = feat + bias; LayerNorm per row (row = rowbase + goff + quad*4 + i,
  // its 128 cols live on the 16 lanes of this quad x 8 tiles)
#define LN_EPILOGUE(ACC, GOFF) do {                                          \
    float s_[4] = {0.f,0.f,0.f,0.f}, ss_[4] = {0.f,0.f,0.f,0.f};             \
    _Pragma("unroll")                                                        \
    for (int t = 0; t < 8; ++t) {                                            \
      _Pragma("unroll")                                                      \
      for (int i = 0; i < 4; ++i) {                                          \
        float h_ = ACC[t][i] + bias[t];                                      \
        ACC[t][i] = h_;                                                      \
        s_[i] += h_; ss_[i] += h_ * h_;                                      \
      }                                                                      \
    }                                                                        \
    _Pragma("unroll")                                                        \
    for (int i = 0; i < 4; ++i) {                                            \
      _Pragma("unroll")                                                      \
      for (int off = 1; off < 16; off <<= 1) {                               \
        s_[i]  += __shfl_xor(s_[i], off);                                    \
        ss_[i] += __shfl_xor(ss_[i], off);                                   \
      }                                                                      \
    }                                                                        \
    _Pragma("unroll")                                                        \
    for (int i = 0; i < 4; ++i) {                                            \
      float mu_  = s_[i] * (1.0f / 128.0f);                                  \
      float var_ = ss_[i] * (1.0f / 128.0f) - mu_ * mu_;                     \
      float inv_ = rsqrtf(var_ + 1e-5f);                                     \
      int r_ = rowbase + (GOFF) + quad * 4 + i;                              \
      float* op_ = out + (size_t)r_ * PD + ln;                               \
      _Pragma("unroll")                                                      \
      for (int t = 0; t < 8; ++t)                                            \
        op_[t * 16] = (ACC[t][i] - mu_) * inv_ * gg[t] + bb[t];              \
    }                                                                        \
  } while (0)

  LN_EPILOGUE(acc0, 0);
  LN_EPILOGUE(acc1, 16);
#undef LN_EPILOGUE
}

// ---------------- launcher ----------------
extern "C" void kernel_launch(void* const* d_in, const int* in_sizes, int n_in,
                              void* d_out, int out_size, void* d_ws, size_t ws_size,
                              hipStream_t stream) {
  const float* x        = (const float*)d_in[0];
  const float* score_w  = (const float*)d_in[1];
  const float* score_b  = (const float*)d_in[2];
  const float* sparse_w = (const float*)d_in[3];
  const float* sparse_b = (const float*)d_in[4];
  const float* full_w   = (const float*)d_in[5];
  const float* full_b   = (const float*)d_in[6];
  const float* ln_g     = (const float*)d_in[7];
  const float* ln_b     = (const float*)d_in[8];
  float* out = (float*)d_out;

  char* ws = (char*)d_ws;
  float*    scores = (float*)ws;                       // B*L f32      (512 KB)
  float*    agg    = (float*)(ws + (512 << 10));       // B*D f32      (16 KB)
  unsigned* wtfg   = (unsigned*)(ws + (528 << 10));    // 2 W panels   (32 KB)
  short*    xbf    = (short*)(ws + (560 << 10));       // B*L*C bf16   (16 MB)

  scores_kernel<<<PB * PL / 128, 256, 0, stream>>>(x, score_w, score_b, sparse_w,
                                                   full_w, scores, xbf, wtfg, agg);
  sparse_kernel<<<PB * (PK / 128), 256, 0, stream>>>(xbf, wtfg, sparse_b, scores, agg);
  full_ln_kernel<<<PB * PL / 128, 256, 0, stream>>>(xbf, wtfg + 4096, full_b,
                                                    ln_g, ln_b, agg, out);
}